// Round 1
// baseline (12986.160 us; speedup 1.0000x reference)
//
#include <hip/hip_runtime.h>

#define WTOT 896   // (2^(K+1)-1)*HIDDEN = 7*128
#define HID 128
#define INF 500
#define NCLS 16

// ---------------- embed GEMM: rf[:,0:128] = relu(x @ w_embed) ----------------
// 64 rows x 128 cols per block, 256 threads, K tiled by 32.
__global__ __launch_bounds__(256) void embed_gemm(
    const float* __restrict__ x, const float* __restrict__ w,
    float* __restrict__ rf, int nrows) {
  __shared__ float xs[64 * 32];    // 8 KB
  __shared__ float ws[32 * 128];   // 16 KB
  const int tid = threadIdx.x;
  const int colq = tid & 31;       // col quad: cols colq*4 .. colq*4+3
  const int rowg = tid >> 5;       // row group: rows rowg*8 .. rowg*8+7
  const int row0 = blockIdx.x * 64;

  float acc[8][4];
#pragma unroll
  for (int r = 0; r < 8; ++r)
#pragma unroll
    for (int j = 0; j < 4; ++j) acc[r][j] = 0.f;

  for (int k0 = 0; k0 < INF; k0 += 32) {
    // load x tile [64][32]
#pragma unroll
    for (int l = 0; l < 8; ++l) {
      int idx = tid + l * 256;
      int rr = idx >> 5, kk = idx & 31;
      int gr = row0 + rr, gk = k0 + kk;
      xs[idx] = (gr < nrows && gk < INF) ? x[(long long)gr * INF + gk] : 0.f;
    }
    // load w tile [32][128]
#pragma unroll
    for (int l = 0; l < 16; ++l) {
      int idx = tid + l * 256;
      int kk = idx >> 7, cc = idx & 127;
      int gk = k0 + kk;
      ws[idx] = (gk < INF) ? w[(long long)gk * HID + cc] : 0.f;
    }
    __syncthreads();
#pragma unroll
    for (int kk = 0; kk < 32; ++kk) {
      float4 wv = *(const float4*)&ws[kk * 128 + colq * 4];
#pragma unroll
      for (int r = 0; r < 8; ++r) {
        float xv = xs[(rowg * 8 + r) * 32 + kk];
        acc[r][0] += xv * wv.x;
        acc[r][1] += xv * wv.y;
        acc[r][2] += xv * wv.z;
        acc[r][3] += xv * wv.w;
      }
    }
    __syncthreads();
  }
#pragma unroll
  for (int r = 0; r < 8; ++r) {
    int gr = row0 + rowg * 8 + r;
    if (gr < nrows) {
      float4 o;
      o.x = fmaxf(acc[r][0], 0.f);
      o.y = fmaxf(acc[r][1], 0.f);
      o.z = fmaxf(acc[r][2], 0.f);
      o.w = fmaxf(acc[r][3], 0.f);
      *(float4*)&rf[(long long)gr * WTOT + colq * 4] = o;
    }
  }
}

// ---------------- COO SpMM scatter: dst[rows[e], :] += vals[e] * relu(src[cols[e], :]) ----
// One thread handles 4 features; group of (width/4) threads per edge.
__global__ void spmm_scatter(
    const int* __restrict__ erows, const int* __restrict__ ecols,
    const float* __restrict__ evals, int nedges,
    const float* __restrict__ rfsrc, int src_col0, int lgG,
    float* __restrict__ rfdst, int dst_col0) {
  long long t = (long long)blockIdx.x * blockDim.x + threadIdx.x;
  long long e = t >> lgG;
  if (e >= nedges) return;
  int f4 = (int)(t & ((1LL << lgG) - 1)) << 2;
  int r = erows[e];
  int c = ecols[e];
  float v = evals[e];
  const float4 s = *(const float4*)&rfsrc[(long long)c * WTOT + src_col0 + f4];
  float* d = &rfdst[(long long)r * WTOT + dst_col0 + f4];
  atomicAdd(d + 0, v * fmaxf(s.x, 0.f));
  atomicAdd(d + 1, v * fmaxf(s.y, 0.f));
  atomicAdd(d + 2, v * fmaxf(s.z, 0.f));
  atomicAdd(d + 3, v * fmaxf(s.w, 0.f));
}

// ---------------- classify: out = softmax(relu-concat(rf) @ wc) ----------------
// One wave (64 lanes) per row: lane = g*16 + c ; g covers k-range [g*224,(g+1)*224).
__global__ __launch_bounds__(256) void classify(
    const float* __restrict__ rf, const float* __restrict__ wc,
    float* __restrict__ out, int nrows) {
  const int row = blockIdx.x * 4 + (threadIdx.x >> 6);
  if (row >= nrows) return;
  const int lane = threadIdx.x & 63;
  const int c = lane & 15;   // class
  const int g = lane >> 4;   // k group
  const float* r = &rf[(long long)row * WTOT];
  float acc = 0.f;
#pragma unroll 8
  for (int i = 0; i < 56; ++i) {
    int kb = g * 224 + i * 4;
    float4 xv = *(const float4*)&r[kb];
    if (kb >= HID) {  // levels >=1 need relu on read (level 0 stored post-relu)
      xv.x = fmaxf(xv.x, 0.f); xv.y = fmaxf(xv.y, 0.f);
      xv.z = fmaxf(xv.z, 0.f); xv.w = fmaxf(xv.w, 0.f);
    }
    acc += xv.x * wc[(kb + 0) * NCLS + c];
    acc += xv.y * wc[(kb + 1) * NCLS + c];
    acc += xv.z * wc[(kb + 2) * NCLS + c];
    acc += xv.w * wc[(kb + 3) * NCLS + c];
  }
  // reduce across the 4 k-groups (lanes differing in bits 4,5)
  acc += __shfl_xor(acc, 16);
  acc += __shfl_xor(acc, 32);
  // softmax over 16 classes (all 4 replicas compute identically)
  float m = acc;
#pragma unroll
  for (int off = 1; off < 16; off <<= 1) m = fmaxf(m, __shfl_xor(m, off));
  float e = __expf(acc - m);
  float s = e;
#pragma unroll
  for (int off = 1; off < 16; off <<= 1) s += __shfl_xor(s, off);
  float p = e / s;
  if (lane < 16) out[(long long)row * NCLS + lane] = p;
}

extern "C" void kernel_launch(void* const* d_in, const int* in_sizes, int n_in,
                              void* d_out, int out_size, void* d_ws, size_t ws_size,
                              hipStream_t stream) {
  const float* x   = (const float*)d_in[0];
  const int*   a1r = (const int*)d_in[1];
  const int*   a1c = (const int*)d_in[2];
  const float* a1v = (const float*)d_in[3];
  const int*   a2r = (const int*)d_in[4];
  const int*   a2c = (const int*)d_in[5];
  const float* a2v = (const float*)d_in[6];
  const float* we  = (const float*)d_in[7];
  const float* wc  = (const float*)d_in[8];
  const int n  = in_sizes[0] / INF;   // 50000
  const int e1 = in_sizes[1];
  const int e2 = in_sizes[4];
  float* rf = (float*)d_ws;           // [n][896]: 0:128=r0, 128:384=lvl1, 384:896=lvl2

  hipMemsetAsync(rf, 0, (size_t)n * WTOT * sizeof(float), stream);

  embed_gemm<<<(n + 63) / 64, 256, 0, stream>>>(x, we, rf, n);

  // round 1: src = r0 (cols 0:128), width 128 (lgG=5)
  {
    long long t1 = (long long)e1 << 5;
    spmm_scatter<<<(unsigned)((t1 + 255) / 256), 256, 0, stream>>>(
        a1r, a1c, a1v, e1, rf, 0, 5, rf, HID);
    long long t2 = (long long)e2 << 5;
    spmm_scatter<<<(unsigned)((t2 + 255) / 256), 256, 0, stream>>>(
        a2r, a2c, a2v, e2, rf, 0, 5, rf, 2 * HID);
  }
  // round 2: src = lvl1 (cols 128:384), width 256 (lgG=6)
  {
    long long t1 = (long long)e1 << 6;
    spmm_scatter<<<(unsigned)((t1 + 255) / 256), 256, 0, stream>>>(
        a1r, a1c, a1v, e1, rf, HID, 6, rf, 3 * HID);
    long long t2 = (long long)e2 << 6;
    spmm_scatter<<<(unsigned)((t2 + 255) / 256), 256, 0, stream>>>(
        a2r, a2c, a2v, e2, rf, HID, 6, rf, 5 * HID);
  }

  classify<<<(n + 3) / 4, 256, 0, stream>>>(rf, wc, (float*)d_out, n);
}

// Round 2
// 1548.122 us; speedup vs baseline: 8.3883x; 8.3883x over previous
//
#include <hip/hip_runtime.h>

#define WTOT 896   // (2^(K+1)-1)*HIDDEN = 7*128
#define HID 128
#define INF 500
#define NCLS 16

// ---------------- embed GEMM: rf[:,0:128] = relu(x @ w_embed) ----------------
__global__ __launch_bounds__(256) void embed_gemm(
    const float* __restrict__ x, const float* __restrict__ w,
    float* __restrict__ rf, int nrows) {
  __shared__ float xs[64 * 32];    // 8 KB
  __shared__ float ws[32 * 128];   // 16 KB
  const int tid = threadIdx.x;
  const int colq = tid & 31;
  const int rowg = tid >> 5;
  const int row0 = blockIdx.x * 64;

  float acc[8][4];
#pragma unroll
  for (int r = 0; r < 8; ++r)
#pragma unroll
    for (int j = 0; j < 4; ++j) acc[r][j] = 0.f;

  for (int k0 = 0; k0 < INF; k0 += 32) {
#pragma unroll
    for (int l = 0; l < 8; ++l) {
      int idx = tid + l * 256;
      int rr = idx >> 5, kk = idx & 31;
      int gr = row0 + rr, gk = k0 + kk;
      xs[idx] = (gr < nrows && gk < INF) ? x[(long long)gr * INF + gk] : 0.f;
    }
#pragma unroll
    for (int l = 0; l < 16; ++l) {
      int idx = tid + l * 256;
      int kk = idx >> 7, cc = idx & 127;
      int gk = k0 + kk;
      ws[idx] = (gk < INF) ? w[(long long)gk * HID + cc] : 0.f;
    }
    __syncthreads();
#pragma unroll
    for (int kk = 0; kk < 32; ++kk) {
      float4 wv = *(const float4*)&ws[kk * 128 + colq * 4];
#pragma unroll
      for (int r = 0; r < 8; ++r) {
        float xv = xs[(rowg * 8 + r) * 32 + kk];
        acc[r][0] += xv * wv.x;
        acc[r][1] += xv * wv.y;
        acc[r][2] += xv * wv.z;
        acc[r][3] += xv * wv.w;
      }
    }
    __syncthreads();
  }
#pragma unroll
  for (int r = 0; r < 8; ++r) {
    int gr = row0 + rowg * 8 + r;
    if (gr < nrows) {
      float4 o;
      o.x = fmaxf(acc[r][0], 0.f);
      o.y = fmaxf(acc[r][1], 0.f);
      o.z = fmaxf(acc[r][2], 0.f);
      o.w = fmaxf(acc[r][3], 0.f);
      *(float4*)&rf[(long long)gr * WTOT + colq * 4] = o;
    }
  }
}

// ---------------- CSR build ----------------
__global__ void count_edges(const int* __restrict__ r1, int e1,
                            const int* __restrict__ r2, int e2,
                            int* __restrict__ deg1, int* __restrict__ deg2) {
  int i = blockIdx.x * blockDim.x + threadIdx.x;
  if (i < e1) atomicAdd(&deg1[r1[i]], 1);
  else if (i < e1 + e2) atomicAdd(&deg2[r2[i - e1]], 1);
}

__global__ __launch_bounds__(256) void scan_rows(
    const int* __restrict__ deg, int* __restrict__ rp, int* __restrict__ cur, int n) {
  __shared__ int sh[256];
  const int t = threadIdx.x;
  const int chunk = (n + 255) >> 8;
  const int lo = t * chunk;
  const int hi = min(lo + chunk, n);
  int s = 0;
  for (int i = lo; i < hi; ++i) s += deg[i];
  sh[t] = s;
  __syncthreads();
  for (int d = 1; d < 256; d <<= 1) {
    int v = (t >= d) ? sh[t - d] : 0;
    __syncthreads();
    sh[t] += v;
    __syncthreads();
  }
  int run = sh[t] - s;  // exclusive prefix
  for (int i = lo; i < hi; ++i) { rp[i] = run; cur[i] = run; run += deg[i]; }
  if (t == 255) rp[n] = sh[255];
}

__global__ void fill_csr(const int* __restrict__ er, const int* __restrict__ ec,
                         const float* __restrict__ ev, int ne,
                         int* __restrict__ cur, int2* __restrict__ pack) {
  int i = blockIdx.x * blockDim.x + threadIdx.x;
  if (i >= ne) return;
  int row = er[i];
  int pos = atomicAdd(&cur[row], 1);
  pack[pos] = make_int2(ec[i], __float_as_int(ev[i]));
}

// ---------------- gather SpMM round 1: width 128, lane=float2 ----------------
__global__ __launch_bounds__(256) void gather_r1(
    const int2* __restrict__ p1, const int* __restrict__ rp1,
    const int2* __restrict__ p2, const int* __restrict__ rp2,
    float* __restrict__ rf, int n) {
  const int row = blockIdx.x * 4 + (threadIdx.x >> 6);
  if (row >= n) return;
  const int lane = threadIdx.x & 63;
  const int f = lane * 2;
  float ax = 0.f, ay = 0.f, bx = 0.f, by = 0.f;
  int j0 = rp1[row], j1 = rp1[row + 1];
  for (int j = j0; j < j1; ++j) {
    int2 cv = p1[j];
    float v = __int_as_float(cv.y);
    float2 s = *(const float2*)&rf[cv.x * WTOT + f];
    ax += v * s.x; ay += v * s.y;
  }
  j0 = rp2[row]; j1 = rp2[row + 1];
  for (int j = j0; j < j1; ++j) {
    int2 cv = p2[j];
    float v = __int_as_float(cv.y);
    float2 s = *(const float2*)&rf[cv.x * WTOT + f];
    bx += v * s.x; by += v * s.y;
  }
  float2 o1 = make_float2(fmaxf(ax, 0.f), fmaxf(ay, 0.f));
  float2 o2 = make_float2(fmaxf(bx, 0.f), fmaxf(by, 0.f));
  *(float2*)&rf[row * WTOT + HID + f] = o1;
  *(float2*)&rf[row * WTOT + 2 * HID + f] = o2;
}

// ---------------- gather SpMM round 2: width 256, lane=float4 ----------------
__global__ __launch_bounds__(256) void gather_r2(
    const int2* __restrict__ p1, const int* __restrict__ rp1,
    const int2* __restrict__ p2, const int* __restrict__ rp2,
    float* __restrict__ rf, int n) {
  const int row = blockIdx.x * 4 + (threadIdx.x >> 6);
  if (row >= n) return;
  const int lane = threadIdx.x & 63;
  const int f = lane * 4;
  float4 a = make_float4(0.f, 0.f, 0.f, 0.f);
  float4 b = make_float4(0.f, 0.f, 0.f, 0.f);
  int j0 = rp1[row], j1 = rp1[row + 1];
  for (int j = j0; j < j1; ++j) {
    int2 cv = p1[j];
    float v = __int_as_float(cv.y);
    float4 s = *(const float4*)&rf[cv.x * WTOT + HID + f];
    a.x += v * s.x; a.y += v * s.y; a.z += v * s.z; a.w += v * s.w;
  }
  j0 = rp2[row]; j1 = rp2[row + 1];
  for (int j = j0; j < j1; ++j) {
    int2 cv = p2[j];
    float v = __int_as_float(cv.y);
    float4 s = *(const float4*)&rf[cv.x * WTOT + HID + f];
    b.x += v * s.x; b.y += v * s.y; b.z += v * s.z; b.w += v * s.w;
  }
  a.x = fmaxf(a.x, 0.f); a.y = fmaxf(a.y, 0.f); a.z = fmaxf(a.z, 0.f); a.w = fmaxf(a.w, 0.f);
  b.x = fmaxf(b.x, 0.f); b.y = fmaxf(b.y, 0.f); b.z = fmaxf(b.z, 0.f); b.w = fmaxf(b.w, 0.f);
  *(float4*)&rf[row * WTOT + 3 * HID + f] = a;
  *(float4*)&rf[row * WTOT + 5 * HID + f] = b;
}

// ---------------- classify: out = softmax(rf @ wc) ----------------
__global__ __launch_bounds__(256) void classify(
    const float* __restrict__ rf, const float* __restrict__ wc,
    float* __restrict__ out, int nrows) {
  const int row = blockIdx.x * 4 + (threadIdx.x >> 6);
  if (row >= nrows) return;
  const int lane = threadIdx.x & 63;
  const int c = lane & 15;
  const int g = lane >> 4;
  const float* r = &rf[(long long)row * WTOT];
  float acc = 0.f;
#pragma unroll 8
  for (int i = 0; i < 56; ++i) {
    int kb = g * 224 + i * 4;
    float4 xv = *(const float4*)&r[kb];
    acc += xv.x * wc[(kb + 0) * NCLS + c];
    acc += xv.y * wc[(kb + 1) * NCLS + c];
    acc += xv.z * wc[(kb + 2) * NCLS + c];
    acc += xv.w * wc[(kb + 3) * NCLS + c];
  }
  acc += __shfl_xor(acc, 16);
  acc += __shfl_xor(acc, 32);
  float m = acc;
#pragma unroll
  for (int off = 1; off < 16; off <<= 1) m = fmaxf(m, __shfl_xor(m, off));
  float e = __expf(acc - m);
  float s = e;
#pragma unroll
  for (int off = 1; off < 16; off <<= 1) s += __shfl_xor(s, off);
  float p = e / s;
  if (lane < 16) out[(long long)row * NCLS + lane] = p;
}

extern "C" void kernel_launch(void* const* d_in, const int* in_sizes, int n_in,
                              void* d_out, int out_size, void* d_ws, size_t ws_size,
                              hipStream_t stream) {
  const float* x   = (const float*)d_in[0];
  const int*   a1r = (const int*)d_in[1];
  const int*   a1c = (const int*)d_in[2];
  const float* a1v = (const float*)d_in[3];
  const int*   a2r = (const int*)d_in[4];
  const int*   a2c = (const int*)d_in[5];
  const float* a2v = (const float*)d_in[6];
  const float* we  = (const float*)d_in[7];
  const float* wc  = (const float*)d_in[8];
  const int n  = in_sizes[0] / INF;   // 50000
  const int e1 = in_sizes[1];         // 1,000,000
  const int e2 = in_sizes[4];         // 1,500,000

  // ---- workspace layout ----
  char* w = (char*)d_ws;
  float* rf  = (float*)w;                                   // n*896*4 = 179.2 MB
  size_t off = (size_t)n * WTOT * sizeof(float);
  int2* pack1 = (int2*)(w + off);  off += (size_t)e1 * 8;   // 8 MB
  int2* pack2 = (int2*)(w + off);  off += (size_t)e2 * 8;   // 12 MB
  int* rp1  = (int*)(w + off);     off += (size_t)(n + 1) * 4;
  int* rp2  = (int*)(w + off);     off += (size_t)(n + 1) * 4;
  int* deg1 = (int*)(w + off);     off += (size_t)n * 4;
  int* deg2 = (int*)(w + off);     off += (size_t)n * 4;
  int* cur1 = (int*)(w + off);     off += (size_t)n * 4;
  int* cur2 = (int*)(w + off);     off += (size_t)n * 4;

  hipMemsetAsync(deg1, 0, (size_t)2 * n * sizeof(int), stream);  // deg1+deg2 adjacent

  embed_gemm<<<(n + 63) / 64, 256, 0, stream>>>(x, we, rf, n);

  int etot = e1 + e2;
  count_edges<<<(etot + 255) / 256, 256, 0, stream>>>(a1r, e1, a2r, e2, deg1, deg2);
  scan_rows<<<1, 256, 0, stream>>>(deg1, rp1, cur1, n);
  scan_rows<<<1, 256, 0, stream>>>(deg2, rp2, cur2, n);
  fill_csr<<<(e1 + 255) / 256, 256, 0, stream>>>(a1r, a1c, a1v, e1, cur1, pack1);
  fill_csr<<<(e2 + 255) / 256, 256, 0, stream>>>(a2r, a2c, a2v, e2, cur2, pack2);

  gather_r1<<<(n + 3) / 4, 256, 0, stream>>>(pack1, rp1, pack2, rp2, rf, n);
  gather_r2<<<(n + 3) / 4, 256, 0, stream>>>(pack1, rp1, pack2, rp2, rf, n);

  classify<<<(n + 3) / 4, 256, 0, stream>>>(rf, wc, (float*)d_out, n);
}

// Round 3
// 839.883 us; speedup vs baseline: 15.4619x; 1.8433x over previous
//
#include <hip/hip_runtime.h>

#define HID 128
#define INF 500
#define NCLS 16
#define PW  112   // proj output width: [s0 | p1 q3a q4a | p2 q3b q4b]
#define T1W 48

// ---------------- embed GEMM: r0 = relu(x @ w_embed), r0 [n,128] ----------------
__global__ __launch_bounds__(256) void embed_gemm(
    const float* __restrict__ x, const float* __restrict__ w,
    float* __restrict__ r0, int nrows) {
  __shared__ float xs[64 * 32];    // 8 KB
  __shared__ float ws[32 * 128];   // 16 KB
  const int tid = threadIdx.x;
  const int colq = tid & 31;
  const int rowg = tid >> 5;
  const int row0 = blockIdx.x * 64;

  float acc[8][4];
#pragma unroll
  for (int r = 0; r < 8; ++r)
#pragma unroll
    for (int j = 0; j < 4; ++j) acc[r][j] = 0.f;

  for (int k0 = 0; k0 < INF; k0 += 32) {
#pragma unroll
    for (int l = 0; l < 8; ++l) {
      int idx = tid + l * 256;
      int rr = idx >> 5, kk = idx & 31;
      int gr = row0 + rr, gk = k0 + kk;
      xs[idx] = (gr < nrows && gk < INF) ? x[(long long)gr * INF + gk] : 0.f;
    }
#pragma unroll
    for (int l = 0; l < 16; ++l) {
      int idx = tid + l * 256;
      int kk = idx >> 7, cc = idx & 127;
      int gk = k0 + kk;
      ws[idx] = (gk < INF) ? w[(long long)gk * HID + cc] : 0.f;
    }
    __syncthreads();
#pragma unroll
    for (int kk = 0; kk < 32; ++kk) {
      float4 wv = *(const float4*)&ws[kk * 128 + colq * 4];
#pragma unroll
      for (int r = 0; r < 8; ++r) {
        float xv = xs[(rowg * 8 + r) * 32 + kk];
        acc[r][0] += xv * wv.x;
        acc[r][1] += xv * wv.y;
        acc[r][2] += xv * wv.z;
        acc[r][3] += xv * wv.w;
      }
    }
    __syncthreads();
  }
#pragma unroll
  for (int r = 0; r < 8; ++r) {
    int gr = row0 + rowg * 8 + r;
    if (gr < nrows) {
      float4 o;
      o.x = fmaxf(acc[r][0], 0.f);
      o.y = fmaxf(acc[r][1], 0.f);
      o.z = fmaxf(acc[r][2], 0.f);
      o.w = fmaxf(acc[r][3], 0.f);
      *(float4*)&r0[(long long)gr * HID + colq * 4] = o;
    }
  }
}

// ---------------- proj GEMM: P[n,112] = r0 @ wc-permuted-blocks ----------------
// P col layout: [0:16]=s0(wc blk0), [16:32]=p1(blk1), [32:48]=q3a(blk3),
// [48:64]=q4a(blk5), [64:80]=p2(blk2), [80:96]=q3b(blk4), [96:112]=q4b(blk6)
__global__ __launch_bounds__(256) void proj_gemm(
    const float* __restrict__ r0, const float* __restrict__ wc,
    float* __restrict__ P, int nrows) {
  __shared__ float xs[64 * 32];     // 8 KB
  __shared__ float ws[32 * PW];     // 14 KB
  const int tid = threadIdx.x;
  const int colq = tid & 31;        // active if < 28
  const int rowg = tid >> 5;
  const int row0 = blockIdx.x * 64;

  float acc[8][4];
#pragma unroll
  for (int r = 0; r < 8; ++r)
#pragma unroll
    for (int j = 0; j < 4; ++j) acc[r][j] = 0.f;

  for (int k0 = 0; k0 < HID; k0 += 32) {
#pragma unroll
    for (int l = 0; l < 8; ++l) {
      int idx = tid + l * 256;
      int rr = idx >> 5, kk = idx & 31;
      int gr = row0 + rr;
      xs[idx] = (gr < nrows) ? r0[(long long)gr * HID + k0 + kk] : 0.f;
    }
#pragma unroll
    for (int l = 0; l < 14; ++l) {
      int idx = tid + l * 256;  // < 3584
      int kk = idx / PW, cc = idx % PW;
      int o = cc >> 4;
      int blk = (o == 0) ? 0 : ((o < 4) ? (2 * o - 1) : (2 * o - 6));
      ws[idx] = wc[(blk * HID + k0 + kk) * NCLS + (cc & 15)];
    }
    __syncthreads();
    if (colq < 28) {
#pragma unroll
      for (int kk = 0; kk < 32; ++kk) {
        float4 wv = *(const float4*)&ws[kk * PW + colq * 4];
#pragma unroll
        for (int r = 0; r < 8; ++r) {
          float xv = xs[(rowg * 8 + r) * 32 + kk];
          acc[r][0] += xv * wv.x;
          acc[r][1] += xv * wv.y;
          acc[r][2] += xv * wv.z;
          acc[r][3] += xv * wv.w;
        }
      }
    }
    __syncthreads();
  }
  if (colq < 28) {
#pragma unroll
    for (int r = 0; r < 8; ++r) {
      int gr = row0 + rowg * 8 + r;
      if (gr < nrows)
        *(float4*)&P[(long long)gr * PW + colq * 4] =
            make_float4(acc[r][0], acc[r][1], acc[r][2], acc[r][3]);
    }
  }
}

// ---------------- CSR build ----------------
__global__ void count_edges(const int* __restrict__ r1, int e1,
                            const int* __restrict__ r2, int e2,
                            int* __restrict__ deg1, int* __restrict__ deg2) {
  int i = blockIdx.x * blockDim.x + threadIdx.x;
  if (i < e1) atomicAdd(&deg1[r1[i]], 1);
  else if (i < e1 + e2) atomicAdd(&deg2[r2[i - e1]], 1);
}

__global__ __launch_bounds__(256) void scan_rows2(
    const int* __restrict__ deg1, int* __restrict__ rp1, int* __restrict__ cur1,
    const int* __restrict__ deg2, int* __restrict__ rp2, int* __restrict__ cur2,
    int n) {
  const int* deg = blockIdx.x ? deg2 : deg1;
  int* rp  = blockIdx.x ? rp2  : rp1;
  int* cur = blockIdx.x ? cur2 : cur1;
  __shared__ int sh[256];
  const int t = threadIdx.x;
  const int chunk = (n + 255) >> 8;
  const int lo = t * chunk;
  const int hi = min(lo + chunk, n);
  int s = 0;
  for (int i = lo; i < hi; ++i) s += deg[i];
  sh[t] = s;
  __syncthreads();
  for (int d = 1; d < 256; d <<= 1) {
    int v = (t >= d) ? sh[t - d] : 0;
    __syncthreads();
    sh[t] += v;
    __syncthreads();
  }
  int run = sh[t] - s;
  for (int i = lo; i < hi; ++i) { rp[i] = run; cur[i] = run; run += deg[i]; }
  if (t == 255) rp[n] = sh[255];
}

__global__ void fill_csr(const int* __restrict__ er, const int* __restrict__ ec,
                         const float* __restrict__ ev, int ne,
                         int* __restrict__ cur, int2* __restrict__ pack) {
  int i = blockIdx.x * blockDim.x + threadIdx.x;
  if (i >= ne) return;
  int row = er[i];
  int pos = atomicAdd(&cur[row], 1);
  pack[pos] = make_int2(ec[i], __float_as_int(ev[i]));
}

// ---------------- SpMM A1 (48-wide): t1[row] = [w1|z3|z4] = sum A1 edges of P[src,16:64]
// wave per row; lane c=lane&15 (col), g=lane>>4 (edge subgroup)
__global__ __launch_bounds__(256) void spmm48_a1(
    const int2* __restrict__ pack, const int* __restrict__ rp,
    const float* __restrict__ P, float* __restrict__ t1, int n) {
  const int row = blockIdx.x * 4 + (threadIdx.x >> 6);
  if (row >= n) return;
  const int lane = threadIdx.x & 63;
  const int c = lane & 15, g = lane >> 4;
  float a0 = 0.f, a1 = 0.f, a2 = 0.f;
  const int j1 = rp[row + 1];
  for (int j = rp[row] + g; j < j1; j += 4) {
    int2 cv = pack[j];
    float v = __int_as_float(cv.y);
    const float* src = &P[(long long)cv.x * PW + 16];
    a0 += v * src[c];
    a1 += v * src[c + 16];
    a2 += v * src[c + 32];
  }
  a0 += __shfl_xor(a0, 16); a0 += __shfl_xor(a0, 32);
  a1 += __shfl_xor(a1, 16); a1 += __shfl_xor(a1, 32);
  a2 += __shfl_xor(a2, 16); a2 += __shfl_xor(a2, 32);
  if (g == 0) {
    float* t = &t1[(long long)row * T1W];
    t[c] = a0; t[c + 16] = a1; t[c + 32] = a2;
  }
}

// ---------------- SpMM A2 (48-wide) + combine:
// [w2|z3'|z4'] = sum A2 edges of P[src,64:112]; then
// wsum[row] = s0 + w1 + w2 ; m34[row] = [z3+z3' | z4+z4']
__global__ __launch_bounds__(256) void spmm48_a2(
    const int2* __restrict__ pack, const int* __restrict__ rp,
    const float* __restrict__ P, const float* __restrict__ t1,
    float* __restrict__ wsum, float* __restrict__ m34, int n) {
  const int row = blockIdx.x * 4 + (threadIdx.x >> 6);
  if (row >= n) return;
  const int lane = threadIdx.x & 63;
  const int c = lane & 15, g = lane >> 4;
  float a0 = 0.f, a1 = 0.f, a2 = 0.f;
  const int j1 = rp[row + 1];
  for (int j = rp[row] + g; j < j1; j += 4) {
    int2 cv = pack[j];
    float v = __int_as_float(cv.y);
    const float* src = &P[(long long)cv.x * PW + 64];
    a0 += v * src[c];
    a1 += v * src[c + 16];
    a2 += v * src[c + 32];
  }
  a0 += __shfl_xor(a0, 16); a0 += __shfl_xor(a0, 32);
  a1 += __shfl_xor(a1, 16); a1 += __shfl_xor(a1, 32);
  a2 += __shfl_xor(a2, 16); a2 += __shfl_xor(a2, 32);
  if (g == 0) {
    const float* t = &t1[(long long)row * T1W];
    float s0 = P[(long long)row * PW + c];
    wsum[(long long)row * 16 + c] = s0 + t[c] + a0;
    m34[(long long)row * 32 + c] = t[c + 16] + a1;
    m34[(long long)row * 32 + 16 + c] = t[c + 32] + a2;
  }
}

// ---------------- final: logits = wsum + A1@m3 + A2@m4; softmax ----------------
__global__ __launch_bounds__(256) void final_spmm_softmax(
    const int2* __restrict__ p1, const int* __restrict__ rp1,
    const int2* __restrict__ p2, const int* __restrict__ rp2,
    const float* __restrict__ wsum, const float* __restrict__ m34,
    float* __restrict__ out, int n) {
  const int row = blockIdx.x * 4 + (threadIdx.x >> 6);
  if (row >= n) return;
  const int lane = threadIdx.x & 63;
  const int c = lane & 15, g = lane >> 4;
  float accA = 0.f, accB = 0.f;
  int j1 = rp1[row + 1];
  for (int j = rp1[row] + g; j < j1; j += 4) {
    int2 cv = p1[j];
    accA += __int_as_float(cv.y) * m34[(long long)cv.x * 32 + c];
  }
  j1 = rp2[row + 1];
  for (int j = rp2[row] + g; j < j1; j += 4) {
    int2 cv = p2[j];
    accB += __int_as_float(cv.y) * m34[(long long)cv.x * 32 + 16 + c];
  }
  accA += __shfl_xor(accA, 16); accA += __shfl_xor(accA, 32);
  accB += __shfl_xor(accB, 16); accB += __shfl_xor(accB, 32);
  float logit = wsum[(long long)row * 16 + c] + accA + accB;
  float m = logit;
#pragma unroll
  for (int off = 1; off < 16; off <<= 1) m = fmaxf(m, __shfl_xor(m, off));
  float e = __expf(logit - m);
  float s = e;
#pragma unroll
  for (int off = 1; off < 16; off <<= 1) s += __shfl_xor(s, off);
  float p = e / s;
  if (lane < 16) out[(long long)row * NCLS + lane] = p;
}

extern "C" void kernel_launch(void* const* d_in, const int* in_sizes, int n_in,
                              void* d_out, int out_size, void* d_ws, size_t ws_size,
                              hipStream_t stream) {
  const float* x   = (const float*)d_in[0];
  const int*   a1r = (const int*)d_in[1];
  const int*   a1c = (const int*)d_in[2];
  const float* a1v = (const float*)d_in[3];
  const int*   a2r = (const int*)d_in[4];
  const int*   a2c = (const int*)d_in[5];
  const float* a2v = (const float*)d_in[6];
  const float* we  = (const float*)d_in[7];
  const float* wc  = (const float*)d_in[8];
  const int n  = in_sizes[0] / INF;   // 50000
  const int e1 = in_sizes[1];         // 1,000,000
  const int e2 = in_sizes[4];         // 1,500,000

  // ---- workspace layout (~90 MB) ----
  char* w = (char*)d_ws;
  size_t off = 0;
  float* r0   = (float*)(w + off); off += (size_t)n * HID * 4;       // 25.6 MB
  float* P    = (float*)(w + off); off += (size_t)n * PW * 4;        // 22.4 MB
  float* t1   = (float*)(w + off); off += (size_t)n * T1W * 4;       //  9.6 MB
  float* wsum = (float*)(w + off); off += (size_t)n * 16 * 4;        //  3.2 MB
  float* m34  = (float*)(w + off); off += (size_t)n * 32 * 4;        //  6.4 MB
  int2* pack1 = (int2*)(w + off);  off += (size_t)e1 * 8;            //  8 MB
  int2* pack2 = (int2*)(w + off);  off += (size_t)e2 * 8;            // 12 MB
  int* rp1  = (int*)(w + off); off += (size_t)(n + 1) * 4;
  int* rp2  = (int*)(w + off); off += (size_t)(n + 1) * 4;
  int* deg1 = (int*)(w + off); off += (size_t)n * 4;
  int* deg2 = (int*)(w + off); off += (size_t)n * 4;
  int* cur1 = (int*)(w + off); off += (size_t)n * 4;
  int* cur2 = (int*)(w + off); off += (size_t)n * 4;

  hipMemsetAsync(deg1, 0, (size_t)2 * n * sizeof(int), stream);  // deg1+deg2 adjacent

  embed_gemm<<<(n + 63) / 64, 256, 0, stream>>>(x, we, r0, n);
  proj_gemm<<<(n + 63) / 64, 256, 0, stream>>>(r0, wc, P, n);

  int etot = e1 + e2;
  count_edges<<<(etot + 255) / 256, 256, 0, stream>>>(a1r, e1, a2r, e2, deg1, deg2);
  scan_rows2<<<2, 256, 0, stream>>>(deg1, rp1, cur1, deg2, rp2, cur2, n);
  fill_csr<<<(e1 + 255) / 256, 256, 0, stream>>>(a1r, a1c, a1v, e1, cur1, pack1);
  fill_csr<<<(e2 + 255) / 256, 256, 0, stream>>>(a2r, a2c, a2v, e2, cur2, pack2);

  spmm48_a1<<<(n + 3) / 4, 256, 0, stream>>>(pack1, rp1, P, t1, n);
  spmm48_a2<<<(n + 3) / 4, 256, 0, stream>>>(pack2, rp2, P, t1, wsum, m34, n);

  final_spmm_softmax<<<(n + 3) / 4, 256, 0, stream>>>(
      pack1, rp1, pack2, rp2, wsum, m34, (float*)d_out, n);
}

// Round 4
// 643.981 us; speedup vs baseline: 20.1654x; 1.3042x over previous
//
#include <hip/hip_runtime.h>

#define HID 128
#define INF 500
#define NCLS 16
#define PW  112   // proj output: [s0 | p1 q3a q4a | p2 q3b q4b]
#define T1W 48

typedef __attribute__((ext_vector_type(8))) short short8v;
typedef __attribute__((ext_vector_type(4))) float f32x4;

// split fp32 into hi (truncated bf16) + lo (bf16 of remainder); v ≈ hi + lo, err ~2^-17|v|
__device__ __forceinline__ void split_bf16(float v, unsigned short& h, unsigned short& l) {
  unsigned u = __float_as_uint(v);
  h = (unsigned short)(u >> 16);
  float hf = __uint_as_float(u & 0xFFFF0000u);
  l = (unsigned short)(__float_as_uint(v - hf) >> 16);
}

__device__ __forceinline__ void cvt8(float4 c0, float4 c1, short8v& h8, short8v& l8) {
  float va[8] = {c0.x, c0.y, c0.z, c0.w, c1.x, c1.y, c1.z, c1.w};
#pragma unroll
  for (int j = 0; j < 8; ++j) {
    unsigned short h, l;
    split_bf16(va[j], h, l);
    h8[j] = (short)h;
    l8[j] = (short)l;
  }
}

// ---------------- B-operand prep: fragment-linear hi/lo bf16 planes ----------------
// B-frag layout for mfma_f32_16x16x32_bf16: lane holds B[k'=(lane>>4)*8+j][n=lane&15].
// we_frag dims: [16 kstep][8 nfrag][64 lane][8 j]
__global__ void prep_we(const float* __restrict__ we, unsigned short* __restrict__ wh,
                        unsigned short* __restrict__ wl) {
  int idx = blockIdx.x * blockDim.x + threadIdx.x;
  if (idx >= 512 * HID) return;
  int k = idx >> 7, nn = idx & 127;
  float v = (k < INF) ? we[k * HID + nn] : 0.f;
  unsigned short h, l;
  split_bf16(v, h, l);
  int kstep = k >> 5, ks = k & 31;
  int lane = (nn & 15) | ((ks >> 3) << 4);
  int j = ks & 7, nf = nn >> 4;
  size_t o = (((size_t)(kstep * 8 + nf)) * 64 + lane) * 8 + j;
  wh[o] = h;
  wl[o] = l;
}

// wcP_frag dims: [4 kstep][7 nfrag][64 lane][8 j]; col blocks of wc permuted [0,1,3,5,2,4,6]
__global__ void prep_wc(const float* __restrict__ wc, unsigned short* __restrict__ ch,
                        unsigned short* __restrict__ cl) {
  int idx = blockIdx.x * blockDim.x + threadIdx.x;
  if (idx >= HID * PW) return;
  int k = idx / PW, np = idx % PW;
  int o = np >> 4;
  int blk = (o == 0) ? 0 : ((o < 4) ? (2 * o - 1) : (2 * o - 6));
  float v = wc[(blk * HID + k) * NCLS + (np & 15)];
  unsigned short h, l;
  split_bf16(v, h, l);
  int kstep = k >> 5, ks = k & 31;
  int lane = (np & 15) | ((ks >> 3) << 4);
  int j = ks & 7, nf = np >> 4;
  size_t of = (((size_t)(kstep * 7 + nf)) * 64 + lane) * 8 + j;
  ch[of] = h;
  cl[of] = l;
}

// ---------------- embed MFMA: r0 = relu(x @ we), bf16x3, no LDS ----------------
// 64 rows/block, 2 waves; wave = 32 rows x 128 cols = 2x8 fragments of 16x16.
__global__ __launch_bounds__(128) void embed_mfma(
    const float* __restrict__ x, const unsigned short* __restrict__ wh,
    const unsigned short* __restrict__ wl, unsigned short* __restrict__ r0h,
    unsigned short* __restrict__ r0l, int n) {
  const int wave = threadIdx.x >> 6, lane = threadIdx.x & 63;
  const int row0 = blockIdx.x * 64 + wave * 32;
  const int rA = lane & 15, kg = lane >> 4;

  f32x4 acc[2][8];
#pragma unroll
  for (int rf = 0; rf < 2; ++rf)
#pragma unroll
    for (int nf = 0; nf < 8; ++nf)
#pragma unroll
      for (int r = 0; r < 4; ++r) acc[rf][nf][r] = 0.f;

  const float* xr0 = &x[(size_t)min(row0 + rA, n - 1) * INF];
  const float* xr1 = &x[(size_t)min(row0 + 16 + rA, n - 1) * INF];

  for (int kstep = 0; kstep < 16; ++kstep) {
    const int kb = kstep * 32 + kg * 8;
    const bool v0 = (kb + 4 <= INF), v1 = (kb + 8 <= INF);
    const int ka0 = v0 ? kb : 0, ka1 = v1 ? kb + 4 : 0;
    float4 z4 = make_float4(0.f, 0.f, 0.f, 0.f);
    float4 a0c0 = *(const float4*)&xr0[ka0]; if (!v0) a0c0 = z4;
    float4 a0c1 = *(const float4*)&xr0[ka1]; if (!v1) a0c1 = z4;
    float4 a1c0 = *(const float4*)&xr1[ka0]; if (!v0) a1c0 = z4;
    float4 a1c1 = *(const float4*)&xr1[ka1]; if (!v1) a1c1 = z4;

    short8v ah[2], al[2];
    cvt8(a0c0, a0c1, ah[0], al[0]);
    cvt8(a1c0, a1c1, ah[1], al[1]);

    const size_t bbase = ((size_t)kstep * 8 * 64 + lane) * 8;
    short8v Bh[8], Bl[8];
#pragma unroll
    for (int nf = 0; nf < 8; ++nf) {
      Bh[nf] = *(const short8v*)&wh[bbase + (size_t)nf * 512];
      Bl[nf] = *(const short8v*)&wl[bbase + (size_t)nf * 512];
    }
#pragma unroll
    for (int rf = 0; rf < 2; ++rf)
#pragma unroll
      for (int nf = 0; nf < 8; ++nf) {
        acc[rf][nf] = __builtin_amdgcn_mfma_f32_16x16x32_bf16(ah[rf], Bh[nf], acc[rf][nf], 0, 0, 0);
        acc[rf][nf] = __builtin_amdgcn_mfma_f32_16x16x32_bf16(ah[rf], Bl[nf], acc[rf][nf], 0, 0, 0);
        acc[rf][nf] = __builtin_amdgcn_mfma_f32_16x16x32_bf16(al[rf], Bh[nf], acc[rf][nf], 0, 0, 0);
      }
  }

  // store relu + split planes; C/D layout: col=lane&15, row=(lane>>4)*4+reg
#pragma unroll
  for (int rf = 0; rf < 2; ++rf)
#pragma unroll
    for (int nf = 0; nf < 8; ++nf) {
      const int row = row0 + rf * 16 + kg * 4;
      const int col = nf * 16 + rA;
#pragma unroll
      for (int r = 0; r < 4; ++r) {
        if (row + r < n) {
          float v = fmaxf(acc[rf][nf][r], 0.f);
          unsigned short h, l;
          split_bf16(v, h, l);
          r0h[(size_t)(row + r) * HID + col] = h;
          r0l[(size_t)(row + r) * HID + col] = l;
        }
      }
    }
}

// ---------------- proj MFMA: P = r0 @ wcP, bf16x3, K=128 ----------------
__global__ __launch_bounds__(128) void proj_mfma(
    const unsigned short* __restrict__ r0h, const unsigned short* __restrict__ r0l,
    const unsigned short* __restrict__ ch, const unsigned short* __restrict__ cl,
    float* __restrict__ P, int n) {
  const int wave = threadIdx.x >> 6, lane = threadIdx.x & 63;
  const int row0 = blockIdx.x * 64 + wave * 32;
  const int rA = lane & 15, kg = lane >> 4;

  f32x4 acc[2][7];
#pragma unroll
  for (int rf = 0; rf < 2; ++rf)
#pragma unroll
    for (int nf = 0; nf < 7; ++nf)
#pragma unroll
      for (int r = 0; r < 4; ++r) acc[rf][nf][r] = 0.f;

  const unsigned short* a0h = &r0h[(size_t)min(row0 + rA, n - 1) * HID];
  const unsigned short* a0l = &r0l[(size_t)min(row0 + rA, n - 1) * HID];
  const unsigned short* a1h = &r0h[(size_t)min(row0 + 16 + rA, n - 1) * HID];
  const unsigned short* a1l = &r0l[(size_t)min(row0 + 16 + rA, n - 1) * HID];

#pragma unroll
  for (int kstep = 0; kstep < 4; ++kstep) {
    const int kb = kstep * 32 + kg * 8;
    short8v ah[2], al[2];
    ah[0] = *(const short8v*)&a0h[kb];
    al[0] = *(const short8v*)&a0l[kb];
    ah[1] = *(const short8v*)&a1h[kb];
    al[1] = *(const short8v*)&a1l[kb];

    const size_t bbase = ((size_t)kstep * 7 * 64 + lane) * 8;
    short8v Bh[7], Bl[7];
#pragma unroll
    for (int nf = 0; nf < 7; ++nf) {
      Bh[nf] = *(const short8v*)&ch[bbase + (size_t)nf * 512];
      Bl[nf] = *(const short8v*)&cl[bbase + (size_t)nf * 512];
    }
#pragma unroll
    for (int rf = 0; rf < 2; ++rf)
#pragma unroll
      for (int nf = 0; nf < 7; ++nf) {
        acc[rf][nf] = __builtin_amdgcn_mfma_f32_16x16x32_bf16(ah[rf], Bh[nf], acc[rf][nf], 0, 0, 0);
        acc[rf][nf] = __builtin_amdgcn_mfma_f32_16x16x32_bf16(ah[rf], Bl[nf], acc[rf][nf], 0, 0, 0);
        acc[rf][nf] = __builtin_amdgcn_mfma_f32_16x16x32_bf16(al[rf], Bh[nf], acc[rf][nf], 0, 0, 0);
      }
  }

#pragma unroll
  for (int rf = 0; rf < 2; ++rf)
#pragma unroll
    for (int nf = 0; nf < 7; ++nf) {
      const int row = row0 + rf * 16 + kg * 4;
      const int col = nf * 16 + rA;
#pragma unroll
      for (int r = 0; r < 4; ++r) {
        if (row + r < n) P[(size_t)(row + r) * PW + col] = acc[rf][nf][r];
      }
    }
}

// ---------------- CSR build ----------------
__global__ void count_edges(const int* __restrict__ r1, int e1,
                            const int* __restrict__ r2, int e2,
                            int* __restrict__ deg1, int* __restrict__ deg2) {
  int i = blockIdx.x * blockDim.x + threadIdx.x;
  if (i < e1) atomicAdd(&deg1[r1[i]], 1);
  else if (i < e1 + e2) atomicAdd(&deg2[r2[i - e1]], 1);
}

__global__ __launch_bounds__(256) void scan_rows2(
    const int* __restrict__ deg1, int* __restrict__ rp1, int* __restrict__ cur1,
    const int* __restrict__ deg2, int* __restrict__ rp2, int* __restrict__ cur2,
    int n) {
  const int* deg = blockIdx.x ? deg2 : deg1;
  int* rp  = blockIdx.x ? rp2  : rp1;
  int* cur = blockIdx.x ? cur2 : cur1;
  __shared__ int sh[256];
  const int t = threadIdx.x;
  const int chunk = (n + 255) >> 8;
  const int lo = t * chunk;
  const int hi = min(lo + chunk, n);
  int s = 0;
  for (int i = lo; i < hi; ++i) s += deg[i];
  sh[t] = s;
  __syncthreads();
  for (int d = 1; d < 256; d <<= 1) {
    int v = (t >= d) ? sh[t - d] : 0;
    __syncthreads();
    sh[t] += v;
    __syncthreads();
  }
  int run = sh[t] - s;
  for (int i = lo; i < hi; ++i) { rp[i] = run; cur[i] = run; run += deg[i]; }
  if (t == 255) rp[n] = sh[255];
}

__global__ void fill_csr2(const int* __restrict__ r1, const int* __restrict__ c1,
                          const float* __restrict__ v1, int e1,
                          const int* __restrict__ r2, const int* __restrict__ c2,
                          const float* __restrict__ v2, int e2,
                          int* __restrict__ cur1, int2* __restrict__ pack1,
                          int* __restrict__ cur2, int2* __restrict__ pack2) {
  int i = blockIdx.x * blockDim.x + threadIdx.x;
  if (i < e1) {
    int pos = atomicAdd(&cur1[r1[i]], 1);
    pack1[pos] = make_int2(c1[i], __float_as_int(v1[i]));
  } else if (i < e1 + e2) {
    int k = i - e1;
    int pos = atomicAdd(&cur2[r2[k]], 1);
    pack2[pos] = make_int2(c2[k], __float_as_int(v2[k]));
  }
}

// ---------------- SpMM A1 (48-wide): t1[row] = sum A1 edges of P[src,16:64] ----------------
__global__ __launch_bounds__(256) void spmm48_a1(
    const int2* __restrict__ pack, const int* __restrict__ rp,
    const float* __restrict__ P, float* __restrict__ t1, int n) {
  const int row = blockIdx.x * 4 + (threadIdx.x >> 6);
  if (row >= n) return;
  const int lane = threadIdx.x & 63;
  const int c = lane & 15, g = lane >> 4;
  float a0 = 0.f, a1 = 0.f, a2 = 0.f;
  const int j1 = rp[row + 1];
  for (int j = rp[row] + g; j < j1; j += 4) {
    int2 cv = pack[j];
    float v = __int_as_float(cv.y);
    const float* src = &P[(long long)cv.x * PW + 16];
    a0 += v * src[c];
    a1 += v * src[c + 16];
    a2 += v * src[c + 32];
  }
  a0 += __shfl_xor(a0, 16); a0 += __shfl_xor(a0, 32);
  a1 += __shfl_xor(a1, 16); a1 += __shfl_xor(a1, 32);
  a2 += __shfl_xor(a2, 16); a2 += __shfl_xor(a2, 32);
  if (g == 0) {
    float* t = &t1[(long long)row * T1W];
    t[c] = a0; t[c + 16] = a1; t[c + 32] = a2;
  }
}

// ---------------- SpMM A2 (48-wide) + combine ----------------
__global__ __launch_bounds__(256) void spmm48_a2(
    const int2* __restrict__ pack, const int* __restrict__ rp,
    const float* __restrict__ P, const float* __restrict__ t1,
    float* __restrict__ wsum, float* __restrict__ m34, int n) {
  const int row = blockIdx.x * 4 + (threadIdx.x >> 6);
  if (row >= n) return;
  const int lane = threadIdx.x & 63;
  const int c = lane & 15, g = lane >> 4;
  float a0 = 0.f, a1 = 0.f, a2 = 0.f;
  const int j1 = rp[row + 1];
  for (int j = rp[row] + g; j < j1; j += 4) {
    int2 cv = pack[j];
    float v = __int_as_float(cv.y);
    const float* src = &P[(long long)cv.x * PW + 64];
    a0 += v * src[c];
    a1 += v * src[c + 16];
    a2 += v * src[c + 32];
  }
  a0 += __shfl_xor(a0, 16); a0 += __shfl_xor(a0, 32);
  a1 += __shfl_xor(a1, 16); a1 += __shfl_xor(a1, 32);
  a2 += __shfl_xor(a2, 16); a2 += __shfl_xor(a2, 32);
  if (g == 0) {
    const float* t = &t1[(long long)row * T1W];
    float s0 = P[(long long)row * PW + c];
    wsum[(long long)row * 16 + c] = s0 + t[c] + a0;
    m34[(long long)row * 32 + c] = t[c + 16] + a1;
    m34[(long long)row * 32 + 16 + c] = t[c + 32] + a2;
  }
}

// ---------------- final: logits = wsum + A1@m3 + A2@m4; softmax ----------------
__global__ __launch_bounds__(256) void final_spmm_softmax(
    const int2* __restrict__ p1, const int* __restrict__ rp1,
    const int2* __restrict__ p2, const int* __restrict__ rp2,
    const float* __restrict__ wsum, const float* __restrict__ m34,
    float* __restrict__ out, int n) {
  const int row = blockIdx.x * 4 + (threadIdx.x >> 6);
  if (row >= n) return;
  const int lane = threadIdx.x & 63;
  const int c = lane & 15, g = lane >> 4;
  float accA = 0.f, accB = 0.f;
  int j1 = rp1[row + 1];
  for (int j = rp1[row] + g; j < j1; j += 4) {
    int2 cv = p1[j];
    accA += __int_as_float(cv.y) * m34[(long long)cv.x * 32 + c];
  }
  j1 = rp2[row + 1];
  for (int j = rp2[row] + g; j < j1; j += 4) {
    int2 cv = p2[j];
    accB += __int_as_float(cv.y) * m34[(long long)cv.x * 32 + 16 + c];
  }
  accA += __shfl_xor(accA, 16); accA += __shfl_xor(accA, 32);
  accB += __shfl_xor(accB, 16); accB += __shfl_xor(accB, 32);
  float logit = wsum[(long long)row * 16 + c] + accA + accB;
  float m = logit;
#pragma unroll
  for (int off = 1; off < 16; off <<= 1) m = fmaxf(m, __shfl_xor(m, off));
  float e = __expf(logit - m);
  float s = e;
#pragma unroll
  for (int off = 1; off < 16; off <<= 1) s += __shfl_xor(s, off);
  float p = e / s;
  if (lane < 16) out[(long long)row * NCLS + lane] = p;
}

extern "C" void kernel_launch(void* const* d_in, const int* in_sizes, int n_in,
                              void* d_out, int out_size, void* d_ws, size_t ws_size,
                              hipStream_t stream) {
  const float* x   = (const float*)d_in[0];
  const int*   a1r = (const int*)d_in[1];
  const int*   a1c = (const int*)d_in[2];
  const float* a1v = (const float*)d_in[3];
  const int*   a2r = (const int*)d_in[4];
  const int*   a2c = (const int*)d_in[5];
  const float* a2v = (const float*)d_in[6];
  const float* we  = (const float*)d_in[7];
  const float* wc  = (const float*)d_in[8];
  const int n  = in_sizes[0] / INF;   // 50000
  const int e1 = in_sizes[1];         // 1,000,000
  const int e2 = in_sizes[4];         // 1,500,000

  // ---- workspace layout (~89 MB) ----
  char* w = (char*)d_ws;
  size_t off = 0;
  unsigned short* r0h = (unsigned short*)(w + off); off += (size_t)n * HID * 2;   // 12.8 MB
  unsigned short* r0l = (unsigned short*)(w + off); off += (size_t)n * HID * 2;   // 12.8 MB
  float* P    = (float*)(w + off); off += (size_t)n * PW * 4;                     // 22.4 MB
  float* t1   = (float*)(w + off); off += (size_t)n * T1W * 4;                    //  9.6 MB
  float* wsum = (float*)(w + off); off += (size_t)n * 16 * 4;                     //  3.2 MB
  float* m34  = (float*)(w + off); off += (size_t)n * 32 * 4;                     //  6.4 MB
  int2* pack1 = (int2*)(w + off);  off += (size_t)e1 * 8;                         //  8 MB
  int2* pack2 = (int2*)(w + off);  off += (size_t)e2 * 8;                         // 12 MB
  unsigned short* wefh = (unsigned short*)(w + off); off += (size_t)512 * HID * 2; // 128 KB
  unsigned short* wefl = (unsigned short*)(w + off); off += (size_t)512 * HID * 2; // 128 KB
  unsigned short* wcfh = (unsigned short*)(w + off); off += (size_t)HID * PW * 2;  // 28.7 KB
  unsigned short* wcfl = (unsigned short*)(w + off); off += (size_t)HID * PW * 2;  // 28.7 KB
  int* rp1  = (int*)(w + off); off += (size_t)(n + 1) * 4;
  int* rp2  = (int*)(w + off); off += (size_t)(n + 1) * 4;
  int* deg1 = (int*)(w + off); off += (size_t)n * 4;
  int* deg2 = (int*)(w + off); off += (size_t)n * 4;
  int* cur1 = (int*)(w + off); off += (size_t)n * 4;
  int* cur2 = (int*)(w + off); off += (size_t)n * 4;

  hipMemsetAsync(deg1, 0, (size_t)2 * n * sizeof(int), stream);  // deg1+deg2 adjacent

  prep_we<<<(512 * HID + 255) / 256, 256, 0, stream>>>(we, wefh, wefl);
  prep_wc<<<(HID * PW + 255) / 256, 256, 0, stream>>>(wc, wcfh, wcfl);

  embed_mfma<<<(n + 63) / 64, 128, 0, stream>>>(x, wefh, wefl, r0h, r0l, n);
  proj_mfma<<<(n + 63) / 64, 128, 0, stream>>>(r0h, r0l, wcfh, wcfl, P, n);

  int etot = e1 + e2;
  count_edges<<<(etot + 255) / 256, 256, 0, stream>>>(a1r, e1, a2r, e2, deg1, deg2);
  scan_rows2<<<2, 256, 0, stream>>>(deg1, rp1, cur1, deg2, rp2, cur2, n);
  fill_csr2<<<(etot + 255) / 256, 256, 0, stream>>>(
      a1r, a1c, a1v, e1, a2r, a2c, a2v, e2, cur1, pack1, cur2, pack2);

  spmm48_a1<<<(n + 3) / 4, 256, 0, stream>>>(pack1, rp1, P, t1, n);
  spmm48_a2<<<(n + 3) / 4, 256, 0, stream>>>(pack2, rp2, P, t1, wsum, m34, n);

  final_spmm_softmax<<<(n + 3) / 4, 256, 0, stream>>>(
      pack1, rp1, pack2, rp2, wsum, m34, (float*)d_out, n);
}